// Round 1
// 609.420 us; speedup vs baseline: 2.5045x; 2.5045x over previous
//
#include <hip/hip_runtime.h>
#include <math.h>

#define NBINS 10
#define TOT_F 51200000.0f
#define NREPL 64          // spread atomic replicas over 64 cache lines
#define REPL_STRIDE 16    // 16 uints = 64 B: one line per replica

typedef float f32x4 __attribute__((ext_vector_type(4)));

// --- numpy float32 np.exp replica (SIMD path: Cephes poly + Cody-Waite) ---
// Bitwise-identical to numpy's AVX2/AVX512 expf for in-range inputs; this is
// what makes the binning bit-exact. DO NOT TOUCH.
__device__ __forceinline__ float np_expf(float x) {
    const float LOG2E = 1.442695040f;          // NPY_LOG2Ef -> 0x3FB8AA3B
    float z = x * LOG2E;
    float q = __builtin_rintf(z);              // round-to-nearest-even
    float r = __builtin_fmaf(q, -0.693359375f, x);
    r = __builtin_fmaf(q, 2.12194440e-4f, r);
    float rr = r * r;
    float p = 1.9875691500e-4f;
    p = __builtin_fmaf(p, r, 1.3981999507e-3f);
    p = __builtin_fmaf(p, r, 8.3334519073e-3f);
    p = __builtin_fmaf(p, r, 4.1665795894e-2f);
    p = __builtin_fmaf(p, r, 1.6666665459e-1f);
    p = __builtin_fmaf(p, r, 5.0000001201e-1f);
    p = __builtin_fmaf(p, rr, r);
    p = p + 1.0f;
    return ldexpf(p, (int)q);
}

// Full fp32 binning chain, matching the numpy reference op-for-op.
__device__ __forceinline__ int bin_index(float x, float t) {
    float e = np_expf(-x);
    float p = 1.0f / (1.0f + e);               // correctly-rounded f32 div
    float g = fabsf(p - t);
    float d = g * 10.0f;
    int idx = (int)d;                          // d >= 0: trunc == floor
    return idx > (NBINS - 1) ? (NBINS - 1) : idx;
}

__global__ void ghm_init_k(unsigned int* __restrict__ counts) {
    int i = threadIdx.x;
    if (i < NREPL * REPL_STRIDE) counts[i] = 0u;
}

__device__ __forceinline__ void acc4(unsigned int c[NBINS], float4 x, float4 t) {
    int i0 = bin_index(x.x, t.x);
    int i1 = bin_index(x.y, t.y);
    int i2 = bin_index(x.z, t.z);
    int i3 = bin_index(x.w, t.w);
#pragma unroll
    for (int b = 0; b < NBINS; ++b)
        c[b] += (unsigned int)(i0 == b) + (unsigned int)(i1 == b) +
                (unsigned int)(i2 == b) + (unsigned int)(i3 == b);
}

// --- pass 1: histogram. Register counters, 4x-unrolled loads for MLP,
// wave shuffle-reduce -> block LDS reduce -> ONE atomic per block per bin,
// spread over 64 replica cache lines (kills same-line atomic serialization).
__global__ void __launch_bounds__(256, 4)
ghm_hist_k(const float4* __restrict__ x4,
           const float4* __restrict__ t4,
           const float*  __restrict__ x1,
           const float*  __restrict__ t1,
           unsigned int* __restrict__ counts,
           int n4, int n) {
    unsigned int c[NBINS];
#pragma unroll
    for (int i = 0; i < NBINS; ++i) c[i] = 0u;

    int gsz = gridDim.x * blockDim.x;
    int i = blockIdx.x * blockDim.x + threadIdx.x;
    int lim = n4 - 3 * gsz;
    for (; i < lim; i += 4 * gsz) {
        float4 xa = x4[i];
        float4 xb = x4[i + gsz];
        float4 xc = x4[i + 2 * gsz];
        float4 xd = x4[i + 3 * gsz];
        float4 ta = t4[i];
        float4 tb = t4[i + gsz];
        float4 tc = t4[i + 2 * gsz];
        float4 td = t4[i + 3 * gsz];
        acc4(c, xa, ta); acc4(c, xb, tb); acc4(c, xc, tc); acc4(c, xd, td);
    }
    for (; i < n4; i += gsz) {
        float4 x = x4[i];
        float4 t = t4[i];
        acc4(c, x, t);
    }
    int tail = n - n4 * 4;
    if (blockIdx.x == 0 && (int)threadIdx.x < tail) {
        int k = n4 * 4 + threadIdx.x;
        int ix = bin_index(x1[k], t1[k]);
#pragma unroll
        for (int b = 0; b < NBINS; ++b) c[b] += (unsigned int)(ix == b);
    }

    __shared__ unsigned int ls[4][NBINS];
    int lane = threadIdx.x & 63;
    int wv = threadIdx.x >> 6;
#pragma unroll
    for (int b = 0; b < NBINS; ++b) {
        unsigned int v = c[b];
#pragma unroll
        for (int off = 32; off > 0; off >>= 1)
            v += __shfl_down(v, off, 64);
        if (lane == 0) ls[wv][b] = v;
    }
    __syncthreads();
    if (threadIdx.x < NBINS) {
        unsigned int s = ls[0][threadIdx.x] + ls[1][threadIdx.x] +
                         ls[2][threadIdx.x] + ls[3][threadIdx.x];
        // replica (blockIdx&63): only blocks == r (mod 64) touch line r,
        // and those all dispatch to the same XCD -> no line ping-pong.
        if (s) atomicAdd(&counts[(blockIdx.x & 63) * REPL_STRIDE + threadIdx.x], s);
    }
}

// --- reduce 64 replicas, then per-bin weights replicating reference fp32 ops.
// counts < 2^24 so (float)count is exact == fp32 segment_sum of ones.
// W is pre-divided by TOT_F (<=2ulp rel. vs reference grouping; budget is 2%).
__global__ void ghm_weights_k(const unsigned int* __restrict__ counts,
                              float* __restrict__ W) {
    __shared__ unsigned int tot[NBINS];
    if (threadIdx.x < NBINS) tot[threadIdx.x] = 0u;
    __syncthreads();
    if (threadIdx.x < NREPL * NBINS) {
        int r = threadIdx.x / NBINS;
        int b = threadIdx.x % NBINS;
        unsigned int v = counts[r * REPL_STRIDE + b];
        if (v) atomicAdd(&tot[b], v);
    }
    __syncthreads();
    if (threadIdx.x == 0) {
        int n = 0;
        for (int i = 0; i < NBINS; ++i) n += (tot[i] > 0u);
        float nf = fmaxf((float)n, 1.0f);
        for (int i = 0; i < NBINS; ++i) {
            float cf = (float)tot[i];
            float bw = (tot[i] > 0u) ? (TOT_F / fmaxf(cf, 1.0f)) : 0.0f;
            W[i] = (bw / nf) / TOT_F;   // fold the final /tot into the table
        }
    }
}

// --- pass 2: elementwise weighted stable BCE. bce precision only needs
// ~1e-6 relative; only the BINNING must be bit-exact.
__device__ __forceinline__ float ghm_elem(float x, float t,
                                          const float* __restrict__ sW) {
    int idx = bin_index(x, t);
    float bce = fmaxf(x, 0.0f) - x * t + log1pf(__expf(-fabsf(x)));
    return sW[idx] * bce;               // /TOT_F already folded into sW
}

__device__ __forceinline__ float4 elem4(float4 x, float4 t,
                                        const float* __restrict__ sW) {
    float4 o;
    o.x = ghm_elem(x.x, t.x, sW);
    o.y = ghm_elem(x.y, t.y, sW);
    o.z = ghm_elem(x.z, t.z, sW);
    o.w = ghm_elem(x.w, t.w, sW);
    return o;
}

__device__ __forceinline__ void nt_store(float4* p, float4 v) {
    __builtin_nontemporal_store(*(f32x4*)&v, (f32x4*)p);
}

__global__ void __launch_bounds__(256, 4)
ghm_main_k(const float4* __restrict__ x4,
           const float4* __restrict__ t4,
           const float*  __restrict__ x1,
           const float*  __restrict__ t1,
           const float*  __restrict__ W,
           float4* __restrict__ o4,
           float*  __restrict__ o1,
           int n4, int n) {
    __shared__ float sW[NBINS];
    if (threadIdx.x < NBINS) sW[threadIdx.x] = W[threadIdx.x];
    __syncthreads();

    int gsz = gridDim.x * blockDim.x;
    int i = blockIdx.x * blockDim.x + threadIdx.x;
    int lim = n4 - 3 * gsz;
    for (; i < lim; i += 4 * gsz) {
        float4 xa = x4[i];
        float4 xb = x4[i + gsz];
        float4 xc = x4[i + 2 * gsz];
        float4 xd = x4[i + 3 * gsz];
        float4 ta = t4[i];
        float4 tb = t4[i + gsz];
        float4 tc = t4[i + 2 * gsz];
        float4 td = t4[i + 3 * gsz];
        nt_store(&o4[i],           elem4(xa, ta, sW));
        nt_store(&o4[i + gsz],     elem4(xb, tb, sW));
        nt_store(&o4[i + 2 * gsz], elem4(xc, tc, sW));
        nt_store(&o4[i + 3 * gsz], elem4(xd, td, sW));
    }
    for (; i < n4; i += gsz) {
        float4 x = x4[i];
        float4 t = t4[i];
        nt_store(&o4[i], elem4(x, t, sW));
    }
    int tail = n - n4 * 4;
    if (blockIdx.x == 0 && (int)threadIdx.x < tail) {
        int k = n4 * 4 + threadIdx.x;
        o1[k] = ghm_elem(x1[k], t1[k], sW);
    }
}

extern "C" void kernel_launch(void* const* d_in, const int* in_sizes, int n_in,
                              void* d_out, int out_size, void* d_ws, size_t ws_size,
                              hipStream_t stream) {
    const float* x = (const float*)d_in[0];
    const float* t = (const float*)d_in[1];
    float* out = (float*)d_out;
    int n  = in_sizes[0];
    int n4 = n >> 2;

    unsigned int* counts = (unsigned int*)d_ws;            // 64*16*4 = 4096 B
    float* W = (float*)((char*)d_ws + NREPL * REPL_STRIDE * 4);  // 10 * 4 B

    const int threads = 256;
    const int blocks  = 2048;   // 8 workgroups/CU on 256 CUs

    ghm_init_k<<<1, 1024, 0, stream>>>(counts);
    ghm_hist_k<<<blocks, threads, 0, stream>>>(
        (const float4*)x, (const float4*)t, x, t, counts, n4, n);
    ghm_weights_k<<<1, 1024, 0, stream>>>(counts, W);
    ghm_main_k<<<blocks, threads, 0, stream>>>(
        (const float4*)x, (const float4*)t, x, t, W,
        (float4*)out, out, n4, n);
}